// Round 8
// baseline (1121.902 us; speedup 1.0000x reference)
//
#include <hip/hip_runtime.h>

typedef unsigned short u16;
typedef unsigned int u32;
typedef __bf16 bf16x8 __attribute__((ext_vector_type(8)));
typedef float f32x4 __attribute__((ext_vector_type(4)));
typedef unsigned long long ull2 __attribute__((ext_vector_type(2)));
typedef unsigned short u16x4 __attribute__((ext_vector_type(4)));

#define BB 2
#define CC 8
#define FF 1024
#define WW 512
#define NH 8
#define DH 128
#define EFF 4096
#define FW (FF * WW)      /* 524288  */
#define PE (WW * EFF)     /* 2097152 */

__device__ __forceinline__ u16 f2b(float f) {
  u32 u = __float_as_uint(f);
  u = u + 0x7FFFu + ((u >> 16) & 1u);
  return (u16)(u >> 16);
}
__device__ __forceinline__ float b2f(u16 b) {
  return __uint_as_float(((u32)b) << 16);
}

// async global->LDS, 16B per lane; LDS dest is wave-uniform base + lane*16
__device__ __forceinline__ void gload_lds16(const u16* g, u16* l) {
  __builtin_amdgcn_global_load_lds(
      (const __attribute__((address_space(1))) u32*)(uintptr_t)g,
      (__attribute__((address_space(3))) u32*)(uintptr_t)l, 16, 0, 0);
}

// ---------------- fp32 -> bf16 weight conversion ----------------
__global__ void f2bf(const float* __restrict__ in, u16* __restrict__ out, long n) {
  long i = ((long)blockIdx.x * 256 + threadIdx.x) * 4;
  if (i >= n) return;
  float4 v = *(const float4*)(in + i);
  u16x4 o;
  o[0] = f2b(v.x); o[1] = f2b(v.y); o[2] = f2b(v.z); o[3] = f2b(v.w);
  *(u16x4*)(out + i) = o;
}

// ---------------- rope cos/sin table [W][64] ----------------
__global__ void rope_table(float2* __restrict__ tab) {
  int i = blockIdx.x * 256 + threadIdx.x;  // 32768
  int w = i >> 6, j = i & 63;
  float invf = powf(10000.f, -(float)(2 * j) / 128.f);
  float fr = (float)w * invf;
  tab[i] = make_float2(cosf(fr), sinf(fr));
}

// ---------------- embed: x[b,2,h,w] -> xr[b,8,h,w] ----------------
__global__ void embed_k(const float* __restrict__ x, const float* __restrict__ ew,
                        const float* __restrict__ eb, float* __restrict__ xr) {
  long i = (long)blockIdx.x * 256 + threadIdx.x;  // 8388608
  int w = (int)(i & (WW - 1));
  long t = i >> 9;
  int h = (int)(t & (FF - 1));
  t >>= 10;
  int d = (int)(t & 7);
  int b = (int)(t >> 3);
  long hw = (long)h * WW + w;
  float v0 = x[((long)(b * 2 + 0)) * FW + hw];
  float v1 = x[((long)(b * 2 + 1)) * FW + hw];
  xr[i] = v0 * ew[d * 2] + v1 * ew[d * 2 + 1] + eb[d];
}

// ---------------- frame-norm stats: per (z,w) over h ----------------
__global__ void norm_stats(const float* __restrict__ x, float* __restrict__ mu,
                           float* __restrict__ rs) {
  int z = blockIdx.x;
  int w0 = blockIdx.y * 32;
  int tw = threadIdx.x & 31, th = threadIdx.x >> 5;  // 8 h-threads per w
  const float* p = x + (long)z * FW + w0 + tw;
  float s = 0.f, s2 = 0.f;
  for (int h = th; h < FF; h += 8) {
    float v = p[(long)h * WW];
    s += v; s2 += v * v;
  }
  __shared__ float ls[8][33], ls2[8][33];
  ls[th][tw] = s; ls2[th][tw] = s2;
  __syncthreads();
  if (th == 0) {
    float a = 0.f, b = 0.f;
#pragma unroll
    for (int j = 0; j < 8; j++) { a += ls[j][tw]; b += ls2[j][tw]; }
    float m = a * (1.f / 1024.f);
    float var = b * (1.f / 1024.f) - m * m;
    mu[z * WW + w0 + tw] = m;
    rs[z * WW + w0 + tw] = rsqrtf(var + 1e-5f);
  }
}

// ------ normalize + transpose: xr[z,h,w] -> nt[z,w,h] bf16 ------
__global__ void norm_apply_t(const float* __restrict__ x, const float* __restrict__ mu,
                             const float* __restrict__ rs, const float* __restrict__ gw,
                             const float* __restrict__ gb, u16* __restrict__ out) {
  int z = blockIdx.x, c = z & 7;
  int w0 = blockIdx.y * 64, h0 = blockIdx.z * 64;
  __shared__ float t[64][65];
  const float* p = x + (long)z * FW;
  int tw = threadIdx.x & 63, tr = threadIdx.x >> 6;
  for (int r = tr; r < 64; r += 4) t[r][tw] = p[(long)(h0 + r) * WW + w0 + tw];
  __syncthreads();
  int hh = threadIdx.x & 63;
  float g = gw[c * FF + h0 + hh], bb = gb[c * FF + h0 + hh];
  for (int r = tr; r < 64; r += 4) {
    int w = w0 + r;
    float m = mu[z * WW + w], q = rs[z * WW + w];
    float v = (t[hh][r] - m) * q * g + bb;
    out[(long)z * FW + (long)w * FF + h0 + hh] = f2b(v);
  }
}

// ---------------- NT MFMA GEMM, 1-D XCD-chunked grid ----------------
// C[row][col] = sum_k A[row][k]*B[col][k], 128x128 tile, BK=32, gload_lds w=16.
// XCD chunking: g = bid&7 selects the XCD-local chunk (assumes round-robin
// blockIdx->XCD); each chunk covers z in {g, g+8} so per-c panels and per-z
// panels stay resident in that XCD's 4MB L2.
// MODE 0: fused QKV. W0/1/2 per-c A-bases; X per-z B; O0/1/2 bf16 outputs.
//         t = p*64 + h*32 + n*8 + m   (1536 blocks)
// MODE 1: lin1. A = X per-z (M=512), B = W0 per-c; O0 bf16 out.
//         t = n*8 + h*4 + m           (2048 blocks)
// MODE 2: split-K (NK chunks), atomicAdd fp32 into OF (pre-initialized).
//         t = kq*64 + h*32 + n*8 + m  (8*64*NK blocks)
template <int MODE, int NK>
__launch_bounds__(256)
__global__ void gemm_sw(const u16* __restrict__ W0, const u16* __restrict__ W1,
                        const u16* __restrict__ W2, const u16* __restrict__ X,
                        u16* O0, u16* O1, u16* O2, float* OF,
                        int K, int lda, int ldb, int ldc,
                        long sWz, long sXz, long sOz) {
  int bid = blockIdx.x;
  int g = bid & 7, t = bid >> 3;
  const u16 *Ap, *Bp;
  u16* Cb = nullptr;
  float* Cfz = nullptr;
  int m0, n0, k_lo, k_hi;
  if (MODE == 0) {
    int p = t / 64, r = t - p * 64;
    int h = r >> 5, q = r & 31;
    n0 = (q >> 3) << 7; m0 = (q & 7) << 7;
    int z = g + (h << 3);
    const u16* W = (p == 0) ? W0 : (p == 1) ? W1 : W2;
    u16* O = (p == 0) ? O0 : (p == 1) ? O1 : O2;
    Ap = W + (long)g * sWz;
    Bp = X + (long)z * sXz;
    Cb = O + (long)z * sOz;
    k_lo = 0; k_hi = K;
  } else if (MODE == 1) {
    int n = t >> 3, r = t & 7;
    int h = r >> 2, m = r & 3;
    n0 = n << 7; m0 = m << 7;
    int z = g + (h << 3);
    Ap = X + (long)z * sXz;
    Bp = W0 + (long)g * sWz;
    Cb = O0 + (long)z * sOz;
    k_lo = 0; k_hi = K;
  } else {
    int kq = t >> 6, r = t & 63;
    int h = r >> 5, q = r & 31;
    n0 = (q >> 3) << 7; m0 = (q & 7) << 7;
    int z = g + (h << 3);
    Ap = W0 + (long)g * sWz;
    Bp = X + (long)z * sXz;
    Cfz = OF + (long)z * sOz;
    int kc = K / NK;
    k_lo = kq * kc; k_hi = k_lo + kc;
  }

  __shared__ __align__(16) u16 As[128 * 32];  // linear: global_load_lds dest
  __shared__ __align__(16) u16 Bs[128 * 32];

  int tid = threadIdx.x;
  int lane = tid & 63, wid = tid >> 6;
  int wr = (wid >> 1) * 64, wc = (wid & 1) * 64;
  int lr = lane & 15, kh = lane >> 4;

  f32x4 acc[4][4];
#pragma unroll
  for (int i = 0; i < 4; i++)
#pragma unroll
    for (int j = 0; j < 4; j++) acc[i][j] = (f32x4){0.f, 0.f, 0.f, 0.f};

  // staging: wave w fills rows [w*32, w*32+32), 2 chunks of 16 rows each.
  int sr = lane >> 2;
  int sc = (lane & 3) * 8;
  const u16* Ag = Ap + (long)(m0 + wid * 32 + sr) * lda + sc;
  const u16* Bg = Bp + (long)(n0 + wid * 32 + sr) * ldb + sc;
  long a16 = (long)16 * lda, b16 = (long)16 * ldb;
  u16* Al0 = As + (wid * 32) * 32;
  u16* Al1 = As + (wid * 32 + 16) * 32;
  u16* Bl0 = Bs + (wid * 32) * 32;
  u16* Bl1 = Bs + (wid * 32 + 16) * 32;

  for (int k0 = k_lo; k0 < k_hi; k0 += 32) {
    gload_lds16(Ag + k0, Al0);
    gload_lds16(Ag + a16 + k0, Al1);
    gload_lds16(Bg + k0, Bl0);
    gload_lds16(Bg + b16 + k0, Bl1);
    __syncthreads();  // compiler drains vmcnt(0) before s_barrier

    const u16* Ar = As + (wr + lr) * 32 + kh * 8;
    const u16* Br = Bs + (wc + lr) * 32 + kh * 8;
    bf16x8 af[4], bfr[4];
#pragma unroll
    for (int m = 0; m < 4; m++) af[m] = *(const bf16x8*)(Ar + m * 16 * 32);
#pragma unroll
    for (int n = 0; n < 4; n++) bfr[n] = *(const bf16x8*)(Br + n * 16 * 32);
#pragma unroll
    for (int m = 0; m < 4; m++)
#pragma unroll
      for (int n = 0; n < 4; n++)
        acc[m][n] = __builtin_amdgcn_mfma_f32_16x16x32_bf16(af[m], bfr[n], acc[m][n], 0, 0, 0);
    __syncthreads();
  }

  int orow = m0 + wr + kh * 4;
  int ocol = n0 + wc + lr;
#pragma unroll
  for (int m = 0; m < 4; m++)
#pragma unroll
    for (int n = 0; n < 4; n++)
#pragma unroll
      for (int j = 0; j < 4; j++) {
        long idx = (long)(orow + m * 16 + j) * ldc + (ocol + n * 16);
        float v = acc[m][n][j];
        if (MODE == 2) atomicAdd(&Cfz[idx], v);
        else Cb[idx] = f2b(v);
      }
}

// ------ depthwise conv(w,3) + RoPE + head-split: lin[z,f,w] -> Q[z,n,w,d] ------
__global__ void conv_rope(const u16* __restrict__ X, const float* __restrict__ cw,
                          const float* __restrict__ cb, const float2* __restrict__ tab,
                          u16* __restrict__ Oq) {
  int z = blockIdx.x, c = z & 7;
  int f0 = blockIdx.y * 32, w0 = blockIdx.z * 64;
  const u16* p = X + (long)z * FW + (long)f0 * WW;
  float c0 = cw[c * 3], c1 = cw[c * 3 + 1], c2 = cw[c * 3 + 2], cbv = cb[c];
  __shared__ float ct[32][65];
  int cc = threadIdx.x & 63, rr = threadIdx.x >> 6;
  int w = w0 + cc;
  for (int r = rr; r < 32; r += 4) {
    const u16* row = p + (long)r * WW + w;
    float xm = (w > 0) ? b2f(row[-1]) : 0.f;
    float x0 = b2f(row[0]);
    float xp = (w < WW - 1) ? b2f(row[1]) : 0.f;
    ct[r][cc] = c0 * xm + c1 * x0 + c2 * xp + cbv;
  }
  __syncthreads();
  int dd = threadIdx.x & 31, wi = threadIdx.x >> 5;
  int nh = f0 >> 7, d0 = f0 & 127;
  int dg = d0 + dd;
  long ob = ((long)(z * NH + nh)) * WW * DH;
  for (int r2 = wi; r2 < 64; r2 += 8) {
    int wg = w0 + r2;
    float2 cs = tab[(long)wg * 64 + (dg >> 1)];
    float xv = ct[dd][r2];
    float v;
    if ((dg & 1) == 0) v = xv * cs.x - ct[dd + 1][r2] * cs.y;
    else               v = xv * cs.x + ct[dd - 1][r2] * cs.y;
    Oq[ob + (long)wg * DH + dg] = f2b(v);
  }
}

// ------ depthwise conv only (V): layout preserved [z,f,w] (= per-head V^T) ------
__global__ void conv_v(const u16* __restrict__ X, const float* __restrict__ cw,
                       const float* __restrict__ cb, u16* __restrict__ Ov) {
  long i = (long)blockIdx.x * 256 + threadIdx.x;  // 8388608
  int w = (int)(i & (WW - 1));
  long t = i >> 9;
  int z = (int)(t >> 10);
  int c = z & 7;
  const u16* row = X + i;
  float xm = (w > 0) ? b2f(row[-1]) : 0.f;
  float x0 = b2f(row[0]);
  float xp = (w < WW - 1) ? b2f(row[1]) : 0.f;
  Ov[i] = f2b(cw[c * 3] * xm + cw[c * 3 + 1] * x0 + cw[c * 3 + 2] * xp + cb[c]);
}

// ---------------- attention: one block per (z, head, 32-row q-tile) ----------------
__launch_bounds__(256)
__global__ void attn_k(const u16* __restrict__ Q, const u16* __restrict__ Kt,
                       const u16* __restrict__ Vt, u16* __restrict__ O) {
  int z = blockIdx.x, n = blockIdx.y, qt = blockIdx.z;
  long hbase = ((long)(z * NH + n)) * WW * DH;
  const u16* Qp = Q + hbase + (long)qt * 32 * DH;
  const u16* Kp = Kt + hbase;
  const u16* Vp = Vt + (long)z * FW + (long)n * DH * WW;

  __shared__ __align__(16) float S[32][516];
  __shared__ __align__(16) u16 Qs[32 * 136];

  int tid = threadIdx.x, lane = tid & 63, wid = tid >> 6;
  int lr = lane & 15, kh = lane >> 4;

#pragma unroll
  for (int p = 0; p < 2; p++) {
    int idx = p * 256 + tid;
    int r = idx >> 4, ch = (idx & 15) * 8;
    *(ull2*)(Qs + r * 136 + ch) = *(const ull2*)(Qp + (long)r * DH + ch);
  }
  __syncthreads();

  f32x4 sacc[2][8];
#pragma unroll
  for (int m = 0; m < 2; m++)
#pragma unroll
    for (int nn = 0; nn < 8; nn++) sacc[m][nn] = (f32x4){0.f, 0.f, 0.f, 0.f};

  const u16* Qr = Qs + lr * 136 + kh * 8;
  const u16* Kr = Kp + (long)(wid * 128 + lr) * DH + kh * 8;
#pragma unroll
  for (int ks = 0; ks < 4; ks++) {
    bf16x8 qa0 = *(const bf16x8*)(Qr + ks * 32);
    bf16x8 qa1 = *(const bf16x8*)(Qr + 16 * 136 + ks * 32);
#pragma unroll
    for (int nn = 0; nn < 8; nn++) {
      bf16x8 kb = *(const bf16x8*)(Kr + (long)nn * 16 * DH + ks * 32);
      sacc[0][nn] = __builtin_amdgcn_mfma_f32_16x16x32_bf16(qa0, kb, sacc[0][nn], 0, 0, 0);
      sacc[1][nn] = __builtin_amdgcn_mfma_f32_16x16x32_bf16(qa1, kb, sacc[1][nn], 0, 0, 0);
    }
  }
#pragma unroll
  for (int m = 0; m < 2; m++)
#pragma unroll
    for (int nn = 0; nn < 8; nn++) {
      int col = wid * 128 + nn * 16 + lr;
      int row = m * 16 + kh * 4;
#pragma unroll
      for (int j = 0; j < 4; j++) S[row + j][col] = sacc[m][nn][j] * 0.03125f;
    }
  __syncthreads();

  int rowi = tid >> 3, sub = tid & 7;
  float mx = -1e30f;
  for (int j = sub; j < 512; j += 8) mx = fmaxf(mx, S[rowi][j]);
#pragma unroll
  for (int o = 1; o < 8; o <<= 1) mx = fmaxf(mx, __shfl_xor(mx, o));
  float sm = 0.f;
  for (int j = sub; j < 512; j += 8) {
    float e = __expf(S[rowi][j] - mx);
    S[rowi][j] = e; sm += e;
  }
#pragma unroll
  for (int o = 1; o < 8; o <<= 1) sm += __shfl_xor(sm, o);
  float inv = 1.f / sm;
  for (int j = sub; j < 512; j += 8) S[rowi][j] *= inv;
  __syncthreads();

  f32x4 oacc[2][2];
#pragma unroll
  for (int m = 0; m < 2; m++)
#pragma unroll
    for (int nn = 0; nn < 2; nn++) oacc[m][nn] = (f32x4){0.f, 0.f, 0.f, 0.f};

  const u16* Vr = Vp + (long)(wid * 32 + lr) * WW;
#pragma unroll 4
  for (int ks = 0; ks < 16; ks++) {
    int kwb = ks * 32 + kh * 8;
    bf16x8 pa[2];
#pragma unroll
    for (int m = 0; m < 2; m++) {
      const float* Pr = &S[m * 16 + lr][kwb];
      f32x4 plo = *(const f32x4*)Pr;
      f32x4 phi = *(const f32x4*)(Pr + 4);
      union { bf16x8 v; u16 s[8]; } pu;
      pu.s[0] = f2b(plo[0]); pu.s[1] = f2b(plo[1]);
      pu.s[2] = f2b(plo[2]); pu.s[3] = f2b(plo[3]);
      pu.s[4] = f2b(phi[0]); pu.s[5] = f2b(phi[1]);
      pu.s[6] = f2b(phi[2]); pu.s[7] = f2b(phi[3]);
      pa[m] = pu.v;
    }
#pragma unroll
    for (int nn = 0; nn < 2; nn++) {
      bf16x8 vb = *(const bf16x8*)(Vr + (long)nn * 16 * WW + kwb);
      oacc[0][nn] = __builtin_amdgcn_mfma_f32_16x16x32_bf16(pa[0], vb, oacc[0][nn], 0, 0, 0);
      oacc[1][nn] = __builtin_amdgcn_mfma_f32_16x16x32_bf16(pa[1], vb, oacc[1][nn], 0, 0, 0);
    }
  }

  long ob = (long)z * WW * FF + (long)n * 128;
#pragma unroll
  for (int m = 0; m < 2; m++)
#pragma unroll
    for (int nn = 0; nn < 2; nn++)
#pragma unroll
      for (int j = 0; j < 4; j++) {
        int qw = qt * 32 + m * 16 + kh * 4 + j;
        int d = wid * 32 + nn * 16 + lr;
        O[ob + (long)qw * FF + d] = f2b(oacc[m][nn][j]);
      }
}

// ------ channel mix (lin1_dw) + relu^2, layout [z][w][e] preserved ------
__global__ void mix_sq(const u16* __restrict__ H, const float* __restrict__ dwm,
                       u16* __restrict__ O) {
  __shared__ float wsm[64];
  if (threadIdx.x < 64) wsm[threadIdx.x] = dwm[threadIdx.x];
  __syncthreads();
  long ti = (long)blockIdx.x * 256 + threadIdx.x;  // 1048576 threads
  int e4 = (int)(ti & 1023);
  int w = (int)((ti >> 10) & (WW - 1));
  int b = (int)(ti >> 19);
  long off = (long)(b * 8) * PE + (long)w * EFF + e4 * 4;
  float v[8][4];
#pragma unroll
  for (int c = 0; c < 8; c++) {
    u16x4 hv = *(const u16x4*)(H + off + (long)c * PE);
    v[c][0] = b2f(hv[0]); v[c][1] = b2f(hv[1]);
    v[c][2] = b2f(hv[2]); v[c][3] = b2f(hv[3]);
  }
#pragma unroll
  for (int d = 0; d < 8; d++) {
    u16x4 ov;
#pragma unroll
    for (int q = 0; q < 4; q++) {
      float s = 0.f;
#pragma unroll
      for (int c = 0; c < 8; c++) s += v[c][q] * wsm[d * 8 + c];
      s = fmaxf(s, 0.f);
      ov[q] = f2b(s * s);
    }
    *(u16x4*)(O + off + (long)d * PE) = ov;
  }
}

extern "C" void kernel_launch(void* const* d_in, const int* in_sizes, int n_in,
                              void* d_out, int out_size, void* d_ws, size_t ws_size,
                              hipStream_t stream) {
  const float* x_in = (const float*)d_in[0];
  const float* ew   = (const float*)d_in[1];
  const float* eb   = (const float*)d_in[2];
  const float* n1w  = (const float*)d_in[3];
  const float* n1b  = (const float*)d_in[4];
  const float* q_pw = (const float*)d_in[5];
  const float* q_cw = (const float*)d_in[6];
  const float* q_cb = (const float*)d_in[7];
  const float* k_pw = (const float*)d_in[8];
  const float* k_cw = (const float*)d_in[9];
  const float* k_cb = (const float*)d_in[10];
  const float* v_pw = (const float*)d_in[11];
  const float* v_cw = (const float*)d_in[12];
  const float* v_cb = (const float*)d_in[13];
  const float* o_pw = (const float*)d_in[14];
  const float* n2w  = (const float*)d_in[15];
  const float* n2b  = (const float*)d_in[16];
  const float* l1pw = (const float*)d_in[17];
  const float* l1dw = (const float*)d_in[18];
  const float* l2pw = (const float*)d_in[19];
  float* out = (float*)d_out;

  if (ws_size < 184877056ULL) return;

  char* ws = (char*)d_ws;
  float*  xr  = (float*)(ws + 0L);            // 33,554,432 B
  u16*    nt  = (u16*)(ws + 33554432L);       // 16,777,216 B
  float*  mu  = (float*)(ws + 50331648L);
  float*  rs  = (float*)(ws + 50364416L);
  float2* tab = (float2*)(ws + 50397184L);
  char* pool  = ws + 50659328L;               // 8 x 16 MB slots
  const long SLOT = 16777216L;
  u16* S0 = (u16*)(pool + 0 * SLOT);
  u16* S1 = (u16*)(pool + 1 * SLOT);
  u16* S2 = (u16*)(pool + 2 * SLOT);
  u16* S3 = (u16*)(pool + 3 * SLOT);
  u16* S4 = (u16*)(pool + 4 * SLOT);
  u16* S5 = (u16*)(pool + 5 * SLOT);

  rope_table<<<128, 256, 0, stream>>>(tab);
  embed_k<<<32768, 256, 0, stream>>>(x_in, ew, eb, xr);

  norm_stats<<<dim3(16, 16), 256, 0, stream>>>(xr, mu, rs);
  norm_apply_t<<<dim3(16, 8, 16), 256, 0, stream>>>(xr, mu, rs, n1w, n1b, nt);

  // fused QKV projection: weights wq/wk/wv -> S0/S1/S2, outputs -> S3/S4/S5
  f2bf<<<8192, 256, 0, stream>>>(q_pw, S0, 8388608L);
  f2bf<<<8192, 256, 0, stream>>>(k_pw, S1, 8388608L);
  f2bf<<<8192, 256, 0, stream>>>(v_pw, S2, 8388608L);
  gemm_sw<0, 1><<<1536, 256, 0, stream>>>(S0, S1, S2, nt, S3, S4, S5, nullptr,
      1024, 1024, 1024, 512, 1048576L, 524288L, 524288L);

  // conv(+rope): qlin=S3 -> Qb=S0, klin=S4 -> Kb=S1, vlin=S5 -> Vtb=S2
  conv_rope<<<dim3(16, 32, 8), 256, 0, stream>>>(S3, q_cw, q_cb, tab, S0);
  conv_rope<<<dim3(16, 32, 8), 256, 0, stream>>>(S4, k_cw, k_cb, tab, S1);
  conv_v<<<32768, 256, 0, stream>>>(S5, v_cw, v_cb, S2);

  // attention: Q=S0 K=S1 Vt=S2 -> amT=S3
  attn_k<<<dim3(16, 8, 16), 256, 0, stream>>>(S0, S1, S2, S3);

  // out projection, split-K=2, atomic accumulate into xr (residual in place)
  f2bf<<<8192, 256, 0, stream>>>(o_pw, S4, 8388608L);
  gemm_sw<2, 2><<<1024, 256, 0, stream>>>(S4, nullptr, nullptr, S3,
      nullptr, nullptr, nullptr, xr,
      1024, 1024, 1024, 512, 1048576L, 524288L, 524288L);

  norm_stats<<<dim3(16, 16), 256, 0, stream>>>(xr, mu, rs);
  norm_apply_t<<<dim3(16, 8, 16), 256, 0, stream>>>(xr, mu, rs, n2w, n2b, nt);

  // lin1: wl1 = S0..S3, hidT = S4..S7
  u16* wl1  = S0;
  u16* hidT = S4;
  f2bf<<<32768, 256, 0, stream>>>(l1pw, wl1, 33554432L);
  gemm_sw<1, 1><<<2048, 256, 0, stream>>>(wl1, nullptr, nullptr, nt,
      hidT, nullptr, nullptr, nullptr,
      1024, 1024, 1024, 4096, 4194304L, 524288L, 2097152L);

  // channel-mix + relu^2: hidT=S4..S7 -> h2T=S0..S3
  u16* h2T = S0;
  mix_sq<<<4096, 256, 0, stream>>>(hidT, l1dw, h2T);

  // lin2: wl2 = S4..S7; out = xr (copy) + atomic split-K=4 accumulate
  u16* wl2 = S4;
  f2bf<<<32768, 256, 0, stream>>>(l2pw, wl2, 33554432L);
  hipMemcpyAsync(out, xr, 33554432L, hipMemcpyDeviceToDevice, stream);
  gemm_sw<2, 4><<<2048, 256, 0, stream>>>(wl2, nullptr, nullptr, h2T,
      nullptr, nullptr, nullptr, out,
      4096, 4096, 4096, 512, 4194304L, 2097152L, 524288L);
}

// Round 10
// 1043.171 us; speedup vs baseline: 1.0755x; 1.0755x over previous
//
#include <hip/hip_runtime.h>

typedef unsigned short u16;
typedef unsigned int u32;
typedef __bf16 bf16x8 __attribute__((ext_vector_type(8)));
typedef float f32x4 __attribute__((ext_vector_type(4)));
typedef unsigned long long ull2 __attribute__((ext_vector_type(2)));
typedef unsigned short u16x4 __attribute__((ext_vector_type(4)));

#define BB 2
#define CC 8
#define FF 1024
#define WW 512
#define NH 8
#define DH 128
#define EFF 4096
#define FW (FF * WW)      /* 524288  */
#define PE (WW * EFF)     /* 2097152 */

__device__ __forceinline__ u16 f2b(float f) {
  u32 u = __float_as_uint(f);
  u = u + 0x7FFFu + ((u >> 16) & 1u);
  return (u16)(u >> 16);
}
__device__ __forceinline__ float b2f(u16 b) {
  return __uint_as_float(((u32)b) << 16);
}

// async global->LDS, 16B per lane; LDS dest is wave-uniform base + lane*16
__device__ __forceinline__ void gload_lds16(const u16* g, u16* l) {
  __builtin_amdgcn_global_load_lds(
      (const __attribute__((address_space(1))) u32*)(uintptr_t)g,
      (__attribute__((address_space(3))) u32*)(uintptr_t)l, 16, 0, 0);
}

// ---------------- fp32 -> bf16 weight conversion ----------------
__global__ void f2bf(const float* __restrict__ in, u16* __restrict__ out, long n) {
  long i = ((long)blockIdx.x * 256 + threadIdx.x) * 4;
  if (i >= n) return;
  float4 v = *(const float4*)(in + i);
  u16x4 o;
  o[0] = f2b(v.x); o[1] = f2b(v.y); o[2] = f2b(v.z); o[3] = f2b(v.w);
  *(u16x4*)(out + i) = o;
}

// ---------------- rope cos/sin table [W][64] ----------------
__global__ void rope_table(float2* __restrict__ tab) {
  int i = blockIdx.x * 256 + threadIdx.x;  // 32768
  int w = i >> 6, j = i & 63;
  float invf = powf(10000.f, -(float)(2 * j) / 128.f);
  float fr = (float)w * invf;
  tab[i] = make_float2(cosf(fr), sinf(fr));
}

// ---------------- embed: x[b,2,h,w] -> xr[b,8,h,w] ----------------
__global__ void embed_k(const float* __restrict__ x, const float* __restrict__ ew,
                        const float* __restrict__ eb, float* __restrict__ xr) {
  long i = (long)blockIdx.x * 256 + threadIdx.x;  // 8388608
  int w = (int)(i & (WW - 1));
  long t = i >> 9;
  int h = (int)(t & (FF - 1));
  t >>= 10;
  int d = (int)(t & 7);
  int b = (int)(t >> 3);
  long hw = (long)h * WW + w;
  float v0 = x[((long)(b * 2 + 0)) * FW + hw];
  float v1 = x[((long)(b * 2 + 1)) * FW + hw];
  xr[i] = v0 * ew[d * 2] + v1 * ew[d * 2 + 1] + eb[d];
}

// ---------------- frame-norm stats: per (z,w) over h ----------------
__global__ void norm_stats(const float* __restrict__ x, float* __restrict__ mu,
                           float* __restrict__ rs) {
  int z = blockIdx.x;
  int w0 = blockIdx.y * 32;
  int tw = threadIdx.x & 31, th = threadIdx.x >> 5;  // 8 h-threads per w
  const float* p = x + (long)z * FW + w0 + tw;
  float s = 0.f, s2 = 0.f;
  for (int h = th; h < FF; h += 8) {
    float v = p[(long)h * WW];
    s += v; s2 += v * v;
  }
  __shared__ float ls[8][33], ls2[8][33];
  ls[th][tw] = s; ls2[th][tw] = s2;
  __syncthreads();
  if (th == 0) {
    float a = 0.f, b = 0.f;
#pragma unroll
    for (int j = 0; j < 8; j++) { a += ls[j][tw]; b += ls2[j][tw]; }
    float m = a * (1.f / 1024.f);
    float var = b * (1.f / 1024.f) - m * m;
    mu[z * WW + w0 + tw] = m;
    rs[z * WW + w0 + tw] = rsqrtf(var + 1e-5f);
  }
}

// ------ normalize + transpose: xr[z,h,w] -> nt[z,w,h] bf16 ------
__global__ void norm_apply_t(const float* __restrict__ x, const float* __restrict__ mu,
                             const float* __restrict__ rs, const float* __restrict__ gw,
                             const float* __restrict__ gb, u16* __restrict__ out) {
  int z = blockIdx.x, c = z & 7;
  int w0 = blockIdx.y * 64, h0 = blockIdx.z * 64;
  __shared__ float t[64][65];
  const float* p = x + (long)z * FW;
  int tw = threadIdx.x & 63, tr = threadIdx.x >> 6;
  for (int r = tr; r < 64; r += 4) t[r][tw] = p[(long)(h0 + r) * WW + w0 + tw];
  __syncthreads();
  int hh = threadIdx.x & 63;
  float g = gw[c * FF + h0 + hh], bb = gb[c * FF + h0 + hh];
  for (int r = tr; r < 64; r += 4) {
    int w = w0 + r;
    float m = mu[z * WW + w], q = rs[z * WW + w];
    float v = (t[hh][r] - m) * q * g + bb;
    out[(long)z * FW + (long)w * FF + h0 + hh] = f2b(v);
  }
}

// ---------------- NT MFMA GEMM, 1-D XCD-chunked grid, double-buffered LDS ----
// C[row][col] = sum_k A[row][k]*B[col][k], 128x128 tile, BK=32, gload_lds w=16.
// Pipeline (guide T3 minimum-2-phase): barrier(buf[cur] ready) -> issue
// stage(buf[cur^1], t+1) -> ds_read+MFMA on buf[cur]. One barrier/iter; the
// next tile's loads are in flight across the whole compute phase.
// MODE 0: fused QKV.  MODE 1: lin1.  MODE 2: split-K atomicAdd into OF.
template <int MODE, int NK>
__launch_bounds__(256)
__global__ void gemm_sw(const u16* __restrict__ W0, const u16* __restrict__ W1,
                        const u16* __restrict__ W2, const u16* __restrict__ X,
                        u16* O0, u16* O1, u16* O2, float* OF,
                        int K, int lda, int ldb, int ldc,
                        long sWz, long sXz, long sOz) {
  int bid = blockIdx.x;
  int g = bid & 7, t = bid >> 3;
  const u16 *Ap, *Bp;
  u16* Cb = nullptr;
  float* Cfz = nullptr;
  int m0, n0, k_lo, k_hi;
  if (MODE == 0) {
    int p = t / 64, r = t - p * 64;
    int h = r >> 5, q = r & 31;
    n0 = (q >> 3) << 7; m0 = (q & 7) << 7;
    int z = g + (h << 3);
    const u16* W = (p == 0) ? W0 : (p == 1) ? W1 : W2;
    u16* O = (p == 0) ? O0 : (p == 1) ? O1 : O2;
    Ap = W + (long)g * sWz;
    Bp = X + (long)z * sXz;
    Cb = O + (long)z * sOz;
    k_lo = 0; k_hi = K;
  } else if (MODE == 1) {
    int n = t >> 3, r = t & 7;
    int h = r >> 2, m = r & 3;
    n0 = n << 7; m0 = m << 7;
    int z = g + (h << 3);
    Ap = X + (long)z * sXz;
    Bp = W0 + (long)g * sWz;
    Cb = O0 + (long)z * sOz;
    k_lo = 0; k_hi = K;
  } else {
    int kq = t >> 6, r = t & 63;
    int h = r >> 5, q = r & 31;
    n0 = (q >> 3) << 7; m0 = (q & 7) << 7;
    int z = g + (h << 3);
    Ap = W0 + (long)g * sWz;
    Bp = X + (long)z * sXz;
    Cfz = OF + (long)z * sOz;
    int kc = K / NK;
    k_lo = kq * kc; k_hi = k_lo + kc;
  }

  __shared__ __align__(16) u16 As[2][128 * 32];  // double buffer, linear dest
  __shared__ __align__(16) u16 Bs[2][128 * 32];

  int tid = threadIdx.x;
  int lane = tid & 63, wid = tid >> 6;
  int wr = (wid >> 1) * 64, wc = (wid & 1) * 64;
  int lr = lane & 15, kh = lane >> 4;

  f32x4 acc[4][4];
#pragma unroll
  for (int i = 0; i < 4; i++)
#pragma unroll
    for (int j = 0; j < 4; j++) acc[i][j] = (f32x4){0.f, 0.f, 0.f, 0.f};

  // staging: wave w fills rows [w*32, w*32+32), 2 chunks of 16 rows each.
  int sr = lane >> 2;
  int sc = (lane & 3) * 8;
  const u16* Ag = Ap + (long)(m0 + wid * 32 + sr) * lda + sc;
  const u16* Bg = Bp + (long)(n0 + wid * 32 + sr) * ldb + sc;
  long a16 = (long)16 * lda, b16 = (long)16 * ldb;
  int lofs0 = (wid * 32) * 32;       // wave-uniform element offsets in a buffer
  int lofs1 = (wid * 32 + 16) * 32;

  // prologue: stage tile 0 into buffer 0
  gload_lds16(Ag + k_lo, &As[0][lofs0]);
  gload_lds16(Ag + a16 + k_lo, &As[0][lofs1]);
  gload_lds16(Bg + k_lo, &Bs[0][lofs0]);
  gload_lds16(Bg + b16 + k_lo, &Bs[0][lofs1]);

  int nt = (k_hi - k_lo) >> 5;
  for (int tt = 0; tt < nt; ++tt) {
    int cur = tt & 1;
    __syncthreads();  // vmcnt(0)+lgkmcnt(0) drain: buf[cur] ready for all waves
    if (tt + 1 < nt) {  // issue next tile AFTER the drain -> in flight over MFMA
      int k1 = k_lo + ((tt + 1) << 5);
      int nb = cur ^ 1;
      gload_lds16(Ag + k1, &As[nb][lofs0]);
      gload_lds16(Ag + a16 + k1, &As[nb][lofs1]);
      gload_lds16(Bg + k1, &Bs[nb][lofs0]);
      gload_lds16(Bg + b16 + k1, &Bs[nb][lofs1]);
    }
    const u16* Ar = &As[cur][(wr + lr) * 32 + kh * 8];
    const u16* Br = &Bs[cur][(wc + lr) * 32 + kh * 8];
    bf16x8 af[4], bfr[4];
#pragma unroll
    for (int m = 0; m < 4; m++) af[m] = *(const bf16x8*)(Ar + m * 16 * 32);
#pragma unroll
    for (int n = 0; n < 4; n++) bfr[n] = *(const bf16x8*)(Br + n * 16 * 32);
#pragma unroll
    for (int m = 0; m < 4; m++)
#pragma unroll
      for (int n = 0; n < 4; n++)
        acc[m][n] = __builtin_amdgcn_mfma_f32_16x16x32_bf16(af[m], bfr[n], acc[m][n], 0, 0, 0);
  }

  int orow = m0 + wr + kh * 4;
  int ocol = n0 + wc + lr;
#pragma unroll
  for (int m = 0; m < 4; m++)
#pragma unroll
    for (int n = 0; n < 4; n++)
#pragma unroll
      for (int j = 0; j < 4; j++) {
        long idx = (long)(orow + m * 16 + j) * ldc + (ocol + n * 16);
        float v = acc[m][n][j];
        if (MODE == 2) atomicAdd(&Cfz[idx], v);
        else Cb[idx] = f2b(v);
      }
}

// ------ depthwise conv(w,3) + RoPE + head-split: lin[z,f,w] -> Q[z,n,w,d] ------
__global__ void conv_rope(const u16* __restrict__ X, const float* __restrict__ cw,
                          const float* __restrict__ cb, const float2* __restrict__ tab,
                          u16* __restrict__ Oq) {
  int z = blockIdx.x, c = z & 7;
  int f0 = blockIdx.y * 32, w0 = blockIdx.z * 64;
  const u16* p = X + (long)z * FW + (long)f0 * WW;
  float c0 = cw[c * 3], c1 = cw[c * 3 + 1], c2 = cw[c * 3 + 2], cbv = cb[c];
  __shared__ float ct[32][65];
  int cc = threadIdx.x & 63, rr = threadIdx.x >> 6;
  int w = w0 + cc;
  for (int r = rr; r < 32; r += 4) {
    const u16* row = p + (long)r * WW + w;
    float xm = (w > 0) ? b2f(row[-1]) : 0.f;
    float x0 = b2f(row[0]);
    float xp = (w < WW - 1) ? b2f(row[1]) : 0.f;
    ct[r][cc] = c0 * xm + c1 * x0 + c2 * xp + cbv;
  }
  __syncthreads();
  int dd = threadIdx.x & 31, wi = threadIdx.x >> 5;
  int nh = f0 >> 7, d0 = f0 & 127;
  int dg = d0 + dd;
  long ob = ((long)(z * NH + nh)) * WW * DH;
  for (int r2 = wi; r2 < 64; r2 += 8) {
    int wg = w0 + r2;
    float2 cs = tab[(long)wg * 64 + (dg >> 1)];
    float xv = ct[dd][r2];
    float v;
    if ((dg & 1) == 0) v = xv * cs.x - ct[dd + 1][r2] * cs.y;
    else               v = xv * cs.x + ct[dd - 1][r2] * cs.y;
    Oq[ob + (long)wg * DH + dg] = f2b(v);
  }
}

// ------ depthwise conv only (V): layout preserved [z,f,w] (= per-head V^T) ------
__global__ void conv_v(const u16* __restrict__ X, const float* __restrict__ cw,
                       const float* __restrict__ cb, u16* __restrict__ Ov) {
  long i = (long)blockIdx.x * 256 + threadIdx.x;  // 8388608
  int w = (int)(i & (WW - 1));
  long t = i >> 9;
  int z = (int)(t >> 10);
  int c = z & 7;
  const u16* row = X + i;
  float xm = (w > 0) ? b2f(row[-1]) : 0.f;
  float x0 = b2f(row[0]);
  float xp = (w < WW - 1) ? b2f(row[1]) : 0.f;
  Ov[i] = f2b(cw[c * 3] * xm + cw[c * 3 + 1] * x0 + cw[c * 3 + 2] * xp + cb[c]);
}

// ---------------- attention: one block per (z, head, 32-row q-tile) ----------------
__launch_bounds__(256)
__global__ void attn_k(const u16* __restrict__ Q, const u16* __restrict__ Kt,
                       const u16* __restrict__ Vt, u16* __restrict__ O) {
  int z = blockIdx.x, n = blockIdx.y, qt = blockIdx.z;
  long hbase = ((long)(z * NH + n)) * WW * DH;
  const u16* Qp = Q + hbase + (long)qt * 32 * DH;
  const u16* Kp = Kt + hbase;
  const u16* Vp = Vt + (long)z * FW + (long)n * DH * WW;

  __shared__ __align__(16) float S[32][516];
  __shared__ __align__(16) u16 Qs[32 * 136];

  int tid = threadIdx.x, lane = tid & 63, wid = tid >> 6;
  int lr = lane & 15, kh = lane >> 4;

#pragma unroll
  for (int p = 0; p < 2; p++) {
    int idx = p * 256 + tid;
    int r = idx >> 4, ch = (idx & 15) * 8;
    *(ull2*)(Qs + r * 136 + ch) = *(const ull2*)(Qp + (long)r * DH + ch);
  }
  __syncthreads();

  f32x4 sacc[2][8];
#pragma unroll
  for (int m = 0; m < 2; m++)
#pragma unroll
    for (int nn = 0; nn < 8; nn++) sacc[m][nn] = (f32x4){0.f, 0.f, 0.f, 0.f};

  const u16* Qr = Qs + lr * 136 + kh * 8;
  const u16* Kr = Kp + (long)(wid * 128 + lr) * DH + kh * 8;
#pragma unroll
  for (int ks = 0; ks < 4; ks++) {
    bf16x8 qa0 = *(const bf16x8*)(Qr + ks * 32);
    bf16x8 qa1 = *(const bf16x8*)(Qr + 16 * 136 + ks * 32);
#pragma unroll
    for (int nn = 0; nn < 8; nn++) {
      bf16x8 kb = *(const bf16x8*)(Kr + (long)nn * 16 * DH + ks * 32);
      sacc[0][nn] = __builtin_amdgcn_mfma_f32_16x16x32_bf16(qa0, kb, sacc[0][nn], 0, 0, 0);
      sacc[1][nn] = __builtin_amdgcn_mfma_f32_16x16x32_bf16(qa1, kb, sacc[1][nn], 0, 0, 0);
    }
  }
#pragma unroll
  for (int m = 0; m < 2; m++)
#pragma unroll
    for (int nn = 0; nn < 8; nn++) {
      int col = wid * 128 + nn * 16 + lr;
      int row = m * 16 + kh * 4;
#pragma unroll
      for (int j = 0; j < 4; j++) S[row + j][col] = sacc[m][nn][j] * 0.03125f;
    }
  __syncthreads();

  int rowi = tid >> 3, sub = tid & 7;
  float mx = -1e30f;
  for (int j = sub; j < 512; j += 8) mx = fmaxf(mx, S[rowi][j]);
#pragma unroll
  for (int o = 1; o < 8; o <<= 1) mx = fmaxf(mx, __shfl_xor(mx, o));
  float sm = 0.f;
  for (int j = sub; j < 512; j += 8) {
    float e = __expf(S[rowi][j] - mx);
    S[rowi][j] = e; sm += e;
  }
#pragma unroll
  for (int o = 1; o < 8; o <<= 1) sm += __shfl_xor(sm, o);
  float inv = 1.f / sm;
  for (int j = sub; j < 512; j += 8) S[rowi][j] *= inv;
  __syncthreads();

  f32x4 oacc[2][2];
#pragma unroll
  for (int m = 0; m < 2; m++)
#pragma unroll
    for (int nn = 0; nn < 2; nn++) oacc[m][nn] = (f32x4){0.f, 0.f, 0.f, 0.f};

  const u16* Vr = Vp + (long)(wid * 32 + lr) * WW;
#pragma unroll 4
  for (int ks = 0; ks < 16; ks++) {
    int kwb = ks * 32 + kh * 8;
    bf16x8 pa[2];
#pragma unroll
    for (int m = 0; m < 2; m++) {
      const float* Pr = &S[m * 16 + lr][kwb];
      f32x4 plo = *(const f32x4*)Pr;
      f32x4 phi = *(const f32x4*)(Pr + 4);
      union { bf16x8 v; u16 s[8]; } pu;
      pu.s[0] = f2b(plo[0]); pu.s[1] = f2b(plo[1]);
      pu.s[2] = f2b(plo[2]); pu.s[3] = f2b(plo[3]);
      pu.s[4] = f2b(phi[0]); pu.s[5] = f2b(phi[1]);
      pu.s[6] = f2b(phi[2]); pu.s[7] = f2b(phi[3]);
      pa[m] = pu.v;
    }
#pragma unroll
    for (int nn = 0; nn < 2; nn++) {
      bf16x8 vb = *(const bf16x8*)(Vr + (long)nn * 16 * WW + kwb);
      oacc[0][nn] = __builtin_amdgcn_mfma_f32_16x16x32_bf16(pa[0], vb, oacc[0][nn], 0, 0, 0);
      oacc[1][nn] = __builtin_amdgcn_mfma_f32_16x16x32_bf16(pa[1], vb, oacc[1][nn], 0, 0, 0);
    }
  }

  long ob = (long)z * WW * FF + (long)n * 128;
#pragma unroll
  for (int m = 0; m < 2; m++)
#pragma unroll
    for (int nn = 0; nn < 2; nn++)
#pragma unroll
      for (int j = 0; j < 4; j++) {
        int qw = qt * 32 + m * 16 + kh * 4 + j;
        int d = wid * 32 + nn * 16 + lr;
        O[ob + (long)qw * FF + d] = f2b(oacc[m][nn][j]);
      }
}

// ------ channel mix (lin1_dw) + relu^2, layout [z][w][e] preserved ------
__global__ void mix_sq(const u16* __restrict__ H, const float* __restrict__ dwm,
                       u16* __restrict__ O) {
  __shared__ float wsm[64];
  if (threadIdx.x < 64) wsm[threadIdx.x] = dwm[threadIdx.x];
  __syncthreads();
  long ti = (long)blockIdx.x * 256 + threadIdx.x;  // 1048576 threads
  int e4 = (int)(ti & 1023);
  int w = (int)((ti >> 10) & (WW - 1));
  int b = (int)(ti >> 19);
  long off = (long)(b * 8) * PE + (long)w * EFF + e4 * 4;
  float v[8][4];
#pragma unroll
  for (int c = 0; c < 8; c++) {
    u16x4 hv = *(const u16x4*)(H + off + (long)c * PE);
    v[c][0] = b2f(hv[0]); v[c][1] = b2f(hv[1]);
    v[c][2] = b2f(hv[2]); v[c][3] = b2f(hv[3]);
  }
#pragma unroll
  for (int d = 0; d < 8; d++) {
    u16x4 ov;
#pragma unroll
    for (int q = 0; q < 4; q++) {
      float s = 0.f;
#pragma unroll
      for (int c = 0; c < 8; c++) s += v[c][q] * wsm[d * 8 + c];
      s = fmaxf(s, 0.f);
      ov[q] = f2b(s * s);
    }
    *(u16x4*)(O + off + (long)d * PE) = ov;
  }
}

extern "C" void kernel_launch(void* const* d_in, const int* in_sizes, int n_in,
                              void* d_out, int out_size, void* d_ws, size_t ws_size,
                              hipStream_t stream) {
  const float* x_in = (const float*)d_in[0];
  const float* ew   = (const float*)d_in[1];
  const float* eb   = (const float*)d_in[2];
  const float* n1w  = (const float*)d_in[3];
  const float* n1b  = (const float*)d_in[4];
  const float* q_pw = (const float*)d_in[5];
  const float* q_cw = (const float*)d_in[6];
  const float* q_cb = (const float*)d_in[7];
  const float* k_pw = (const float*)d_in[8];
  const float* k_cw = (const float*)d_in[9];
  const float* k_cb = (const float*)d_in[10];
  const float* v_pw = (const float*)d_in[11];
  const float* v_cw = (const float*)d_in[12];
  const float* v_cb = (const float*)d_in[13];
  const float* o_pw = (const float*)d_in[14];
  const float* n2w  = (const float*)d_in[15];
  const float* n2b  = (const float*)d_in[16];
  const float* l1pw = (const float*)d_in[17];
  const float* l1dw = (const float*)d_in[18];
  const float* l2pw = (const float*)d_in[19];
  float* out = (float*)d_out;

  if (ws_size < 184877056ULL) return;

  char* ws = (char*)d_ws;
  float*  xr  = (float*)(ws + 0L);            // 33,554,432 B
  u16*    nt  = (u16*)(ws + 33554432L);       // 16,777,216 B
  float*  mu  = (float*)(ws + 50331648L);
  float*  rs  = (float*)(ws + 50364416L);
  float2* tab = (float2*)(ws + 50397184L);
  char* pool  = ws + 50659328L;               // 8 x 16 MB slots
  const long SLOT = 16777216L;
  u16* S0 = (u16*)(pool + 0 * SLOT);
  u16* S1 = (u16*)(pool + 1 * SLOT);
  u16* S2 = (u16*)(pool + 2 * SLOT);
  u16* S3 = (u16*)(pool + 3 * SLOT);
  u16* S4 = (u16*)(pool + 4 * SLOT);
  u16* S5 = (u16*)(pool + 5 * SLOT);

  rope_table<<<128, 256, 0, stream>>>(tab);
  embed_k<<<32768, 256, 0, stream>>>(x_in, ew, eb, xr);

  norm_stats<<<dim3(16, 16), 256, 0, stream>>>(xr, mu, rs);
  norm_apply_t<<<dim3(16, 8, 16), 256, 0, stream>>>(xr, mu, rs, n1w, n1b, nt);

  // fused QKV projection: weights wq/wk/wv -> S0/S1/S2, outputs -> S3/S4/S5
  f2bf<<<8192, 256, 0, stream>>>(q_pw, S0, 8388608L);
  f2bf<<<8192, 256, 0, stream>>>(k_pw, S1, 8388608L);
  f2bf<<<8192, 256, 0, stream>>>(v_pw, S2, 8388608L);
  gemm_sw<0, 1><<<1536, 256, 0, stream>>>(S0, S1, S2, nt, S3, S4, S5, nullptr,
      1024, 1024, 1024, 512, 1048576L, 524288L, 524288L);

  // conv(+rope): qlin=S3 -> Qb=S0, klin=S4 -> Kb=S1, vlin=S5 -> Vtb=S2
  conv_rope<<<dim3(16, 32, 8), 256, 0, stream>>>(S3, q_cw, q_cb, tab, S0);
  conv_rope<<<dim3(16, 32, 8), 256, 0, stream>>>(S4, k_cw, k_cb, tab, S1);
  conv_v<<<32768, 256, 0, stream>>>(S5, v_cw, v_cb, S2);

  // attention: Q=S0 K=S1 Vt=S2 -> amT=S3
  attn_k<<<dim3(16, 8, 16), 256, 0, stream>>>(S0, S1, S2, S3);

  // out projection, split-K=2, atomic accumulate into xr (residual in place)
  f2bf<<<8192, 256, 0, stream>>>(o_pw, S4, 8388608L);
  gemm_sw<2, 2><<<1024, 256, 0, stream>>>(S4, nullptr, nullptr, S3,
      nullptr, nullptr, nullptr, xr,
      1024, 1024, 1024, 512, 1048576L, 524288L, 524288L);

  norm_stats<<<dim3(16, 16), 256, 0, stream>>>(xr, mu, rs);
  norm_apply_t<<<dim3(16, 8, 16), 256, 0, stream>>>(xr, mu, rs, n2w, n2b, nt);

  // lin1: wl1 = S0..S3, hidT = S4..S7
  u16* wl1  = S0;
  u16* hidT = S4;
  f2bf<<<32768, 256, 0, stream>>>(l1pw, wl1, 33554432L);
  gemm_sw<1, 1><<<2048, 256, 0, stream>>>(wl1, nullptr, nullptr, nt,
      hidT, nullptr, nullptr, nullptr,
      1024, 1024, 1024, 4096, 4194304L, 524288L, 2097152L);

  // channel-mix + relu^2: hidT=S4..S7 -> h2T=S0..S3
  u16* h2T = S0;
  mix_sq<<<4096, 256, 0, stream>>>(hidT, l1dw, h2T);

  // lin2: wl2 = S4..S7; out = xr (copy) + atomic split-K=4 accumulate
  u16* wl2 = S4;
  f2bf<<<32768, 256, 0, stream>>>(l2pw, wl2, 33554432L);
  hipMemcpyAsync(out, xr, 33554432L, hipMemcpyDeviceToDevice, stream);
  gemm_sw<2, 4><<<2048, 256, 0, stream>>>(wl2, nullptr, nullptr, h2T,
      nullptr, nullptr, nullptr, out,
      4096, 4096, 4096, 512, 4194304L, 2097152L, 524288L);
}